// Round 7
// baseline (286.032 us; speedup 1.0000x reference)
//
#include <hip/hip_runtime.h>
#include <stdint.h>

#define NN 8192
#define EE 262144
#define DD 128
#define NEGS 0.2f
#define HBITS 19
#define HSIZE (1<<HBITS)
#define HMASK (HSIZE-1)
#define BCAP 256

typedef float f32x4 __attribute__((ext_vector_type(4)));

__device__ __forceinline__ unsigned f2ord(float f){
  unsigned u = __float_as_uint(f);
  return (u & 0x80000000u) ? ~u : (u | 0x80000000u);
}
__device__ __forceinline__ float ord2f(unsigned u){
  return __uint_as_float((u & 0x80000000u) ? (u & 0x7fffffffu) : ~u);
}
__device__ __forceinline__ unsigned hmix(int key){
  unsigned h = (unsigned)key * 2654435761u;
  h ^= h >> 15;
  return h;
}

// ---- setup: clear hash/cnt/T/fillmax + transpose W ----
__global__ void k_setup(int* hkeys, int* hvals, int* cnt, float* T,
                        unsigned* fillmax, const float* __restrict__ W,
                        float* __restrict__ wt){
  int gid = blockIdx.x*256 + threadIdx.x;      // 1024 blocks -> 262144 threads
  int4 m1 = {-1,-1,-1,-1};
  if(gid < HSIZE/4)            ((int4*)hkeys)[gid] = m1;
  else if(gid < HSIZE/2)       ((int4*)hvals)[gid - HSIZE/4] = m1;
  if(gid < NN/4)               ((int4*)cnt)[gid] = int4{0,0,0,0};
  if(gid < DD/4)               ((float4*)T)[gid] = float4{0.f,0.f,0.f,0.f};
  if(gid == 0)                 *fillmax = 0x007FFFFFu;   // f2ord(-inf)
  if(gid < DD*DD){
    int c = gid >> 7, k = gid & 127;
    wt[k*DD + c] = W[gid];
  }
}

// ---- h_trans = h @ W^T, with fused a1/a2 (att dots) and column-sum T ----
__global__ __launch_bounds__(256) void k_gemm(const float* __restrict__ h,
    const float* __restrict__ wt, const float* __restrict__ att,
    float* __restrict__ ht, float* a1, float* a2, float* T){
  __shared__ float wl[64*DD];
  __shared__ float hl[16][132];
  __shared__ float pa[2][4][16];
  int t = threadIdx.x;
  int row0 = blockIdx.x * 16;
  #pragma unroll
  for(int u=0;u<2;u++){
    int f4 = u*256 + t;
    int r = f4 >> 5, k4 = f4 & 31;
    float4 v = ((const float4*)(h + (size_t)(row0+r)*DD))[k4];
    *((float4*)&hl[r][k4*4]) = v;
  }
  int r  = t & 15;
  int c0 = (t >> 4) * 8;
  float acc[8];
  #pragma unroll
  for(int s=0;s<8;s++) acc[s]=0.f;
  for(int p=0;p<2;p++){
    __syncthreads();
    const float4* wsrc = (const float4*)(wt + p*64*DD);
    float4* wd = (float4*)wl;
    #pragma unroll
    for(int u=0;u<8;u++) wd[u*256+t] = wsrc[u*256+t];
    __syncthreads();
    #pragma unroll 2
    for(int kk=0;kk<64;kk++){
      float hv = hl[r][p*64+kk];
      const float4* wr4 = (const float4*)&wl[kk*DD + c0];
      float4 w0 = wr4[0], w1 = wr4[1];
      acc[0] += hv*w0.x; acc[1] += hv*w0.y; acc[2] += hv*w0.z; acc[3] += hv*w0.w;
      acc[4] += hv*w1.x; acc[5] += hv*w1.y; acc[6] += hv*w1.z; acc[7] += hv*w1.w;
    }
  }
  // store ht
  float4* o = (float4*)(ht + (size_t)(row0+r)*DD + c0);
  o[0] = float4{acc[0],acc[1],acc[2],acc[3]};
  o[1] = float4{acc[4],acc[5],acc[6],acc[7]};
  // ---- fused epilogue: a1/a2 per row, column sums for T ----
  const float4* at4 = (const float4*)att;
  float4 A0 = at4[(c0>>2)], A1 = at4[(c0>>2)+1];
  float4 B0 = at4[32+(c0>>2)], B1 = at4[32+(c0>>2)+1];
  float p1 = acc[0]*A0.x+acc[1]*A0.y+acc[2]*A0.z+acc[3]*A0.w
           + acc[4]*A1.x+acc[5]*A1.y+acc[6]*A1.z+acc[7]*A1.w;
  float p2 = acc[0]*B0.x+acc[1]*B0.y+acc[2]*B0.z+acc[3]*B0.w
           + acc[4]*B1.x+acc[5]*B1.y+acc[6]*B1.z+acc[7]*B1.w;
  // sum over the 4 lanes in this wave holding the same row r (bits 4,5)
  p1 += __shfl_xor(p1,16); p1 += __shfl_xor(p1,32);
  p2 += __shfl_xor(p2,16); p2 += __shfl_xor(p2,32);
  int w = t >> 6, lid = t & 63;
  if(lid < 16){ pa[0][w][lid] = p1; pa[1][w][lid] = p2; }
  // column sums over the 16 rows (16 consecutive lanes share c0)
  float cs[8];
  #pragma unroll
  for(int s=0;s<8;s++){
    float v = acc[s];
    v += __shfl_down(v,8); v += __shfl_down(v,4);
    v += __shfl_down(v,2); v += __shfl_down(v,1);
    cs[s] = v;
  }
  __syncthreads();
  if(t < 16){
    a1[row0+t] = pa[0][0][t]+pa[0][1][t]+pa[0][2][t]+pa[0][3][t];
    a2[row0+t] = pa[1][0][t]+pa[1][1][t]+pa[1][2][t]+pa[1][3][t];
  }
  if((t & 15) == 0){
    #pragma unroll
    for(int s=0;s<8;s++) atomicAdd(&T[c0+s], cs[s]);
  }
}

// ---- per-edge: leaky value, global max, hash insert (last-write-wins) ----
__global__ void k_edge(const int* __restrict__ ei, const float* __restrict__ a1,
                       const float* __restrict__ a2, float* __restrict__ val,
                       unsigned* fillmax, int* hkeys, int* hvals){
  int k = blockIdx.x*256 + threadIdx.x;
  int r = ei[k], c = ei[EE + k];
  float e = a1[r] + a2[c];
  e = e >= 0.f ? e : NEGS*e;
  val[k] = e;
  float wm = e;
  #pragma unroll
  for(int o=32;o>0;o>>=1) wm = fmaxf(wm, __shfl_down(wm,o));
  __shared__ float sm[4];
  if((threadIdx.x & 63)==0) sm[threadIdx.x>>6] = wm;
  __syncthreads();
  if(threadIdx.x==0){
    float bm = fmaxf(fmaxf(sm[0],sm[1]), fmaxf(sm[2],sm[3]));
    atomicMax(fillmax, f2ord(bm));
  }
  if(r != c){
    int key = (r<<13) | c;
    unsigned slot = hmix(key) & HMASK;
    while(true){
      int prev = atomicCAS(&hkeys[slot], -1, key);
      if(prev == -1 || prev == key){ atomicMax(&hvals[slot], k); break; }
      slot = (slot + 1) & HMASK;
    }
  }
}

// ---- hash -> symmetrized entries into per-row buckets ----
__global__ void k_fill(const int* __restrict__ hkeys, const int* __restrict__ hvals,
                       const float* __restrict__ val, int* cnt,
                       int2* __restrict__ bucket){
  int base = (blockIdx.x*256 + threadIdx.x) * 2;
  #pragma unroll
  for(int u=0;u<2;u++){
    int s = base + u;
    int key = hkeys[s];
    if(key < 0) continue;
    int i = key >> 13, j = key & (NN-1);
    int kwin = hvals[s];
    int rkey = (j<<13) | i;
    unsigned slot = hmix(rkey) & HMASK;
    int krev = -1;
    while(true){
      int kk = hkeys[slot];
      if(kk == rkey){ krev = hvals[slot]; break; }
      if(kk == -1) break;
      slot = (slot + 1) & HMASK;
    }
    float a = 0.5f * (val[kwin] + (krev >= 0 ? val[krev] : 0.f));
    int p = atomicAdd(&cnt[i], 1);
    if(p < BCAP) bucket[((size_t)i<<8) + p] = int2{j, __float_as_int(a)};
    if(krev < 0){
      int q = atomicAdd(&cnt[j], 1);
      if(q < BCAP) bucket[((size_t)j<<8) + q] = int2{i, __float_as_int(a)};
    }
  }
}

// ---- per-row stats + h' (wave per row). m is row-uniform: max(fill,0). ----
__global__ __launch_bounds__(256) void k_rowstats(const float* __restrict__ ht,
    const float* __restrict__ T, const int* __restrict__ cnt,
    const int2* __restrict__ bucket, const unsigned* __restrict__ fillmax,
    float* inv_, float* z_, float* dg_, float* __restrict__ hprime){
  int lane = threadIdx.x & 63;
  int i = blockIdx.x*4 + (threadIdx.x >> 6);
  float fill = ord2f(*fillmax);
  float m = fmaxf(fill, 0.f);
  int n = min(cnt[i], BCAP);
  const int2* brow = bucket + ((size_t)i<<8);
  float ds = 0.f;
  for(int e=lane; e<n; e+=64) ds += __expf(__int_as_float(brow[e].y) - m);
  #pragma unroll
  for(int o=32;o>0;o>>=1) ds += __shfl_xor(ds,o);
  float ez = __expf(-m);
  float ef = __expf(fill - m);
  float denom = ds + ef + (float)(NN-1-n)*ez;
  float invd = 1.f/denom;
  if(lane==0){ inv_[i]=invd; z_[i]=ez*invd; dg_[i]=ef*invd; }
  const float* hti = ht + (size_t)i*DD;
  float acc0 = ez*T[lane]    + (ef-ez)*hti[lane];
  float acc1 = ez*T[lane+64] + (ef-ez)*hti[lane+64];
  for(int e=0;e<n;e++){
    int2 be = brow[e];
    float w = __expf(__int_as_float(be.y) - m) - ez;
    const float* htj = ht + (size_t)be.x*DD;
    acc0 += w*htj[lane];
    acc1 += w*htj[lane+64];
  }
  acc0 *= invd; acc1 *= invd;
  acc0 = acc0 > 0.f ? acc0 : expm1f(acc0);
  acc1 = acc1 > 0.f ? acc1 : expm1f(acc1);
  hprime[(size_t)i*DD + lane]      = acc0;
  hprime[(size_t)i*DD + lane + 64] = acc1;
}

// ---- dense row write: LDS rowbuf = z, patch sparse+diag, NT stream out ----
__global__ __launch_bounds__(256) void k_dense(const int* __restrict__ cnt,
    const int2* __restrict__ bucket, const unsigned* __restrict__ fillmax,
    const float* __restrict__ inv_, const float* __restrict__ z_,
    const float* __restrict__ dg_, float* __restrict__ attn){
  __shared__ float rowbuf[NN];     // 32KB
  int i = blockIdx.x, t = threadIdx.x;
  float z = z_[i];
  f32x4 zv = {z,z,z,z};
  f32x4* rb4 = (f32x4*)rowbuf;
  #pragma unroll
  for(int u=0;u<8;u++) rb4[u*256+t] = zv;
  __syncthreads();
  int n = min(cnt[i], BCAP);
  if(t < n){
    float m = fmaxf(ord2f(*fillmax), 0.f);
    int2 be = bucket[((size_t)i<<8) + t];
    rowbuf[be.x] = __expf(__int_as_float(be.y) - m) * inv_[i];
  }
  if(t==0) rowbuf[i] = dg_[i];
  __syncthreads();
  f32x4* o = (f32x4*)(attn + ((size_t)i<<13));
  #pragma unroll
  for(int u=0;u<8;u++) __builtin_nontemporal_store(rb4[u*256+t], o + u*256+t);
}

extern "C" void kernel_launch(void* const* d_in, const int* in_sizes, int n_in,
                              void* d_out, int out_size, void* d_ws, size_t ws_size,
                              hipStream_t stream){
  const float* h   = (const float*)d_in[0];
  const int*   ei  = (const int*)d_in[1];
  const float* W   = (const float*)d_in[2];
  const float* att = (const float*)d_in[3];
  float* out = (float*)d_out;
  float* hprime = out;                       // [N, D]
  float* attn   = out + (size_t)NN*DD;       // [N, N]

  // Early scratch (consumed before k_dense) in the dead attn output region.
  int*   hkeys = (int*)attn;                          // 2 MB
  int*   hvals = hkeys + HSIZE;                       // 2 MB
  float* val   = (float*)(hvals + HSIZE);             // 1 MB
  float* a1    = val + EE;                            // 32 KB
  float* a2    = a1 + NN;                             // 32 KB

  // Scratch read by rowstats/dense in d_ws (~21 MB).
  char* ws = (char*)d_ws;
  size_t off = 0;
  auto alloc = [&](size_t bytes)->char*{
    char* p = ws + off;
    off = (off + bytes + 255) & ~(size_t)255;
    return p;
  };
  float* ht      = (float*)alloc((size_t)NN*DD*4);        // 4 MB
  float* wt      = (float*)alloc((size_t)DD*DD*4);        // 64 KB
  float* T       = (float*)alloc((size_t)DD*4);
  int*   cnt     = (int*)alloc((size_t)NN*4);
  float* inv_    = (float*)alloc((size_t)NN*4);
  float* z_      = (float*)alloc((size_t)NN*4);
  float* dg_     = (float*)alloc((size_t)NN*4);
  unsigned* fillmax = (unsigned*)alloc(256);
  int2*  bucket  = (int2*)alloc((size_t)NN*BCAP*8);       // 16 MB

  k_setup   <<<1024, 256, 0, stream>>>(hkeys, hvals, cnt, T, fillmax, W, wt);
  k_gemm    <<<NN/16, 256, 0, stream>>>(h, wt, att, ht, a1, a2, T);
  k_edge    <<<EE/256, 256, 0, stream>>>(ei, a1, a2, val, fillmax, hkeys, hvals);
  k_fill    <<<HSIZE/512, 256, 0, stream>>>(hkeys, hvals, val, cnt, bucket);
  k_rowstats<<<NN/4, 256, 0, stream>>>(ht, T, cnt, bucket, fillmax, inv_, z_, dg_, hprime);
  k_dense   <<<NN, 256, 0, stream>>>(cnt, bucket, fillmax, inv_, z_, dg_, attn);
}

// Round 8
// 204.121 us; speedup vs baseline: 1.4013x; 1.4013x over previous
//
#include <hip/hip_runtime.h>
#include <stdint.h>

#define NN 8192
#define EE 262144
#define DD 128
#define NEGS 0.2f
#define HBITS 19
#define HSIZE (1<<HBITS)
#define HMASK (HSIZE-1)
#define BCAP 256

typedef float f32x4 __attribute__((ext_vector_type(4)));

__device__ __forceinline__ unsigned f2ord(float f){
  unsigned u = __float_as_uint(f);
  return (u & 0x80000000u) ? ~u : (u | 0x80000000u);
}
__device__ __forceinline__ float ord2f(unsigned u){
  return __uint_as_float((u & 0x80000000u) ? (u & 0x7fffffffu) : ~u);
}
__device__ __forceinline__ unsigned hmix(int key){
  unsigned h = (unsigned)key * 2654435761u;
  h ^= h >> 15;
  return h;
}

// ---- setup: clear hash/cnt/T/fillmax + transpose W ----
__global__ void k_setup(int* hkeys, int* hvals, int* cnt, float* T,
                        unsigned* fillmax, const float* __restrict__ W,
                        float* __restrict__ wt){
  int gid = blockIdx.x*256 + threadIdx.x;      // 1024 blocks -> 262144 threads
  int4 m1 = {-1,-1,-1,-1};
  if(gid < HSIZE/4)            ((int4*)hkeys)[gid] = m1;
  else if(gid < HSIZE/2)       ((int4*)hvals)[gid - HSIZE/4] = m1;
  if(gid < NN/4)               ((int4*)cnt)[gid] = int4{0,0,0,0};
  if(gid < DD/4)               ((float4*)T)[gid] = float4{0.f,0.f,0.f,0.f};
  if(gid == 0)                 *fillmax = 0x007FFFFFu;   // f2ord(-inf)
  if(gid < DD*DD){
    int c = gid >> 7, k = gid & 127;
    wt[k*DD + c] = W[gid];
  }
}

// ---- h_trans = h @ W^T ----
__global__ __launch_bounds__(256) void k_gemm(const float* __restrict__ h,
                                              const float* __restrict__ wt,
                                              float* __restrict__ ht){
  __shared__ float wl[64*DD];
  __shared__ float hl[16][132];
  int t = threadIdx.x;
  int row0 = blockIdx.x * 16;
  #pragma unroll
  for(int u=0;u<2;u++){
    int f4 = u*256 + t;
    int r = f4 >> 5, k4 = f4 & 31;
    float4 v = ((const float4*)(h + (size_t)(row0+r)*DD))[k4];
    *((float4*)&hl[r][k4*4]) = v;
  }
  int r  = t & 15;
  int c0 = (t >> 4) * 8;
  float acc[8];
  #pragma unroll
  for(int s=0;s<8;s++) acc[s]=0.f;
  for(int p=0;p<2;p++){
    __syncthreads();
    const float4* wsrc = (const float4*)(wt + p*64*DD);
    float4* wd = (float4*)wl;
    #pragma unroll
    for(int u=0;u<8;u++) wd[u*256+t] = wsrc[u*256+t];
    __syncthreads();
    #pragma unroll 2
    for(int kk=0;kk<64;kk++){
      float hv = hl[r][p*64+kk];
      const float4* wr4 = (const float4*)&wl[kk*DD + c0];
      float4 w0 = wr4[0], w1 = wr4[1];
      acc[0] += hv*w0.x; acc[1] += hv*w0.y; acc[2] += hv*w0.z; acc[3] += hv*w0.w;
      acc[4] += hv*w1.x; acc[5] += hv*w1.y; acc[6] += hv*w1.z; acc[7] += hv*w1.w;
    }
  }
  float4* o = (float4*)(ht + (size_t)(row0+r)*DD + c0);
  o[0] = float4{acc[0],acc[1],acc[2],acc[3]};
  o[1] = float4{acc[4],acc[5],acc[6],acc[7]};
}

// ---- fused: a1/a2 per node + column-sum T ----
__global__ __launch_bounds__(256) void k_stats(const float* __restrict__ ht,
    const float* __restrict__ att, float* T, float* a1, float* a2){
  int t = threadIdx.x, b = blockIdx.x;
  int lane = t & 63;
  int i = b*4 + (t >> 6);
  const float* hr = ht + (size_t)i*DD;
  float h0 = hr[lane], h1 = hr[lane+64];
  float x1 = h0*att[lane]    + h1*att[lane+64];
  float x2 = h0*att[DD+lane] + h1*att[DD+lane+64];
  #pragma unroll
  for(int o=32;o>0;o>>=1){ x1 += __shfl_down(x1,o); x2 += __shfl_down(x2,o); }
  if(lane==0){ a1[i]=x1; a2[i]=x2; }
  if(b < 64){
    __shared__ float part[256];
    int c = t & 127, half = t >> 7;
    float s = 0.f;
    int r0 = b*128 + half*64;
    for(int rr=r0; rr<r0+64; rr++) s += ht[(size_t)rr*DD + c];
    part[t] = s; __syncthreads();
    if(half==0) atomicAdd(&T[c], part[t] + part[t+128]);
  }
}

// ---- per-edge: leaky value, global max, hash insert (last-write-wins) ----
__global__ void k_edge(const int* __restrict__ ei, const float* __restrict__ a1,
                       const float* __restrict__ a2, float* __restrict__ val,
                       unsigned* fillmax, int* hkeys, int* hvals){
  int k = blockIdx.x*256 + threadIdx.x;
  int r = ei[k], c = ei[EE + k];
  float e = a1[r] + a2[c];
  e = e >= 0.f ? e : NEGS*e;
  val[k] = e;
  float wm = e;
  #pragma unroll
  for(int o=32;o>0;o>>=1) wm = fmaxf(wm, __shfl_down(wm,o));
  __shared__ float sm[4];
  if((threadIdx.x & 63)==0) sm[threadIdx.x>>6] = wm;
  __syncthreads();
  if(threadIdx.x==0){
    float bm = fmaxf(fmaxf(sm[0],sm[1]), fmaxf(sm[2],sm[3]));
    atomicMax(fillmax, f2ord(bm));
  }
  if(r != c){
    int key = (r<<13) | c;
    unsigned slot = hmix(key) & HMASK;
    while(true){
      int prev = atomicCAS(&hkeys[slot], -1, key);
      if(prev == -1 || prev == key){ atomicMax(&hvals[slot], k); break; }
      slot = (slot + 1) & HMASK;
    }
  }
}

// ---- hash -> symmetrized entries into per-row buckets ----
__global__ void k_fill(const int* __restrict__ hkeys, const int* __restrict__ hvals,
                       const float* __restrict__ val, int* cnt,
                       int2* __restrict__ bucket){
  int base = (blockIdx.x*256 + threadIdx.x) * 2;
  #pragma unroll
  for(int u=0;u<2;u++){
    int s = base + u;
    int key = hkeys[s];
    if(key < 0) continue;
    int i = key >> 13, j = key & (NN-1);
    int kwin = hvals[s];
    int rkey = (j<<13) | i;
    unsigned slot = hmix(rkey) & HMASK;
    int krev = -1;
    while(true){
      int kk = hkeys[slot];
      if(kk == rkey){ krev = hvals[slot]; break; }
      if(kk == -1) break;
      slot = (slot + 1) & HMASK;
    }
    float a = 0.5f * (val[kwin] + (krev >= 0 ? val[krev] : 0.f));
    int p = atomicAdd(&cnt[i], 1);
    if(p < BCAP) bucket[((size_t)i<<8) + p] = int2{j, __float_as_int(a)};
    if(krev < 0){
      int q = atomicAdd(&cnt[j], 1);
      if(q < BCAP) bucket[((size_t)j<<8) + q] = int2{i, __float_as_int(a)};
    }
  }
}

// ---- per-row stats + h' (wave per row). m is row-uniform: max(fill,0). ----
__global__ __launch_bounds__(256) void k_rowstats(const float* __restrict__ ht,
    const float* __restrict__ T, const int* __restrict__ cnt,
    const int2* __restrict__ bucket, const unsigned* __restrict__ fillmax,
    float* inv_, float* z_, float* dg_, float* __restrict__ hprime){
  int lane = threadIdx.x & 63;
  int i = blockIdx.x*4 + (threadIdx.x >> 6);
  float fill = ord2f(*fillmax);
  float m = fmaxf(fill, 0.f);
  int n = min(cnt[i], BCAP);
  const int2* brow = bucket + ((size_t)i<<8);
  float ds = 0.f;
  for(int e=lane; e<n; e+=64) ds += __expf(__int_as_float(brow[e].y) - m);
  #pragma unroll
  for(int o=32;o>0;o>>=1) ds += __shfl_xor(ds,o);
  float ez = __expf(-m);
  float ef = __expf(fill - m);
  float denom = ds + ef + (float)(NN-1-n)*ez;
  float invd = 1.f/denom;
  if(lane==0){ inv_[i]=invd; z_[i]=ez*invd; dg_[i]=ef*invd; }
  const float* hti = ht + (size_t)i*DD;
  float acc0 = ez*T[lane]    + (ef-ez)*hti[lane];
  float acc1 = ez*T[lane+64] + (ef-ez)*hti[lane+64];
  for(int e=0;e<n;e++){
    int2 be = brow[e];
    float w = __expf(__int_as_float(be.y) - m) - ez;
    const float* htj = ht + (size_t)be.x*DD;
    acc0 += w*htj[lane];
    acc1 += w*htj[lane+64];
  }
  acc0 *= invd; acc1 *= invd;
  acc0 = acc0 > 0.f ? acc0 : expm1f(acc0);
  acc1 = acc1 > 0.f ? acc1 : expm1f(acc1);
  hprime[(size_t)i*DD + lane]      = acc0;
  hprime[(size_t)i*DD + lane + 64] = acc1;
}

// ---- dense row write: LDS rowbuf = z, patch sparse+diag, NT stream out ----
__global__ __launch_bounds__(256) void k_dense(const int* __restrict__ cnt,
    const int2* __restrict__ bucket, const unsigned* __restrict__ fillmax,
    const float* __restrict__ inv_, const float* __restrict__ z_,
    const float* __restrict__ dg_, float* __restrict__ attn){
  __shared__ float rowbuf[NN];     // 32KB
  int i = blockIdx.x, t = threadIdx.x;
  float z = z_[i];
  f32x4 zv = {z,z,z,z};
  f32x4* rb4 = (f32x4*)rowbuf;
  #pragma unroll
  for(int u=0;u<8;u++) rb4[u*256+t] = zv;
  __syncthreads();
  int n = min(cnt[i], BCAP);
  if(t < n){
    float m = fmaxf(ord2f(*fillmax), 0.f);
    int2 be = bucket[((size_t)i<<8) + t];
    rowbuf[be.x] = __expf(__int_as_float(be.y) - m) * inv_[i];
  }
  if(t==0) rowbuf[i] = dg_[i];
  __syncthreads();
  f32x4* o = (f32x4*)(attn + ((size_t)i<<13));
  #pragma unroll
  for(int u=0;u<8;u++) __builtin_nontemporal_store(rb4[u*256+t], o + u*256+t);
}

extern "C" void kernel_launch(void* const* d_in, const int* in_sizes, int n_in,
                              void* d_out, int out_size, void* d_ws, size_t ws_size,
                              hipStream_t stream){
  const float* h   = (const float*)d_in[0];
  const int*   ei  = (const int*)d_in[1];
  const float* W   = (const float*)d_in[2];
  const float* att = (const float*)d_in[3];
  float* out = (float*)d_out;
  float* hprime = out;                       // [N, D]
  float* attn   = out + (size_t)NN*DD;       // [N, N]

  // Early scratch (consumed before k_dense) in the dead attn output region.
  int*   hkeys = (int*)attn;                          // 2 MB
  int*   hvals = hkeys + HSIZE;                       // 2 MB
  float* val   = (float*)(hvals + HSIZE);             // 1 MB
  float* a1    = val + EE;                            // 32 KB
  float* a2    = a1 + NN;                             // 32 KB

  // Scratch read by rowstats/dense in d_ws (~21 MB).
  char* ws = (char*)d_ws;
  size_t off = 0;
  auto alloc = [&](size_t bytes)->char*{
    char* p = ws + off;
    off = (off + bytes + 255) & ~(size_t)255;
    return p;
  };
  float* ht      = (float*)alloc((size_t)NN*DD*4);        // 4 MB
  float* wt      = (float*)alloc((size_t)DD*DD*4);        // 64 KB
  float* T       = (float*)alloc((size_t)DD*4);
  int*   cnt     = (int*)alloc((size_t)NN*4);
  float* inv_    = (float*)alloc((size_t)NN*4);
  float* z_      = (float*)alloc((size_t)NN*4);
  float* dg_     = (float*)alloc((size_t)NN*4);
  unsigned* fillmax = (unsigned*)alloc(256);
  int2*  bucket  = (int2*)alloc((size_t)NN*BCAP*8);       // 16 MB

  k_setup   <<<1024, 256, 0, stream>>>(hkeys, hvals, cnt, T, fillmax, W, wt);
  k_gemm    <<<NN/16, 256, 0, stream>>>(h, wt, ht);
  k_stats   <<<NN/4, 256, 0, stream>>>(ht, att, T, a1, a2);
  k_edge    <<<EE/256, 256, 0, stream>>>(ei, a1, a2, val, fillmax, hkeys, hvals);
  k_fill    <<<HSIZE/512, 256, 0, stream>>>(hkeys, hvals, val, cnt, bucket);
  k_rowstats<<<NN/4, 256, 0, stream>>>(ht, T, cnt, bucket, fillmax, inv_, z_, dg_, hprime);
  k_dense   <<<NN, 256, 0, stream>>>(cnt, bucket, fillmax, inv_, z_, dg_, attn);
}